// Round 7
// baseline (377.830 us; speedup 1.0000x reference)
//
#include <hip/hip_runtime.h>
#include <hip/hip_bf16.h>
#include <cstdint>
#include <cstddef>

// B=4, S=2048, D=1024. Inputs fp32 (runtime-detected, bf16 fallback kept).
// GEMMs: 256x128 block tile, BK=64 (two slabs), global_load_lds width-16
// staging with parity-independent XOR kgroup swizzle, 4 waves each computing
// 128x64 via 4x2 32x32x16 bf16 MFMAs (21.3 FLOP per LDS-byte vs 16 before).
//
// Pipeline:
//   0. detect_mode; convert bias/gamma/beta + X -> bf16; transpose W -> Wt
//   1. gemm256: QKV[8192][3072] = Xb @ Wt^T + bias                  (bf16)
//   2. gemm256 z=4: S4[b][2048][2048] = (Q_b @ K_b^T)/32            (bf16)
//   3. softmax_bf16: in-place row softmax on S4 -> P                (bf16)
//   4. transpose_v4 z=4: Vt4[b][1024][2048] = V_b^T
//   5. gemm256 z=4: Ctx_b = P_b @ V_b -> dead Q slots of QKV        (bf16)
//   6. resid_ln: out = LN(Ctx + Xb)*gamma + beta (fp32 or bf16 store)
//
// d_ws layout (16B-aligned, ~118 MB):
//   flag  @ 0            16
//   bias5 @ 16           10,240
//   Wt    @ 16,384       6,291,456
//   QKV   @ 6,307,840    50,331,648
//   Xb    @ 56,639,488   16,777,216
//   S4/P4 @ 73,416,704   33,554,432
//   Vt4   @ 106,971,136  16,777,216   (end 123,748,352)

typedef unsigned short u16;
using bf16x8 = __attribute__((ext_vector_type(8))) short;
using f32x16 = __attribute__((ext_vector_type(16))) float;

typedef __attribute__((address_space(3))) unsigned int lds_uint;
typedef const __attribute__((address_space(1))) unsigned int glob_uint;

__device__ __forceinline__ float bf2f(u16 h) {
    union { unsigned int u; float f; } c;
    c.u = ((unsigned int)h) << 16;
    return c.f;
}
__device__ __forceinline__ u16 f2bf(float f) {
    union { float f; unsigned int u; } c;
    c.f = f;
    return (u16)((c.u + 0x7fffu + ((c.u >> 16) & 1u)) >> 16);  // RNE
}
__device__ __forceinline__ void load_lds16(const void* g, void* l) {
    __builtin_amdgcn_global_load_lds((glob_uint*)g, (lds_uint*)l, 16, 0, 0);
}

// ------------------------------------------------------------- mode detection
__global__ void detect_mode_kernel(const u16* __restrict__ X, int* __restrict__ flag)
{
    const int lane = threadIdx.x;      // 64 threads
    bool bad = false, nz = false;
    for (int j = 0; j < 4; ++j) {
        float v = bf2f(X[(lane * 4 + j) * 2]);
        if (!(fabsf(v) <= 1e9f)) bad = true;
        if (v != 0.f) nz = true;
    }
    unsigned long long anybad = __ballot(bad);
    unsigned long long anynz  = __ballot(nz);
    if (lane == 0) *flag = (anybad != 0ull || anynz == 0ull) ? 1 : 0;
}

// --------------------------------------------------- small vectors -> bf16
__global__ __launch_bounds__(256) void convert_small_kernel(
    const void* s0, const void* s1, const void* s2, const void* s3,
    const void* s4, u16* __restrict__ dst, const int* __restrict__ flag)
{
    const void* srcs[5] = {s0, s1, s2, s3, s4};
    const void* src = srcs[blockIdx.x];
    u16* d = dst + (size_t)blockIdx.x * 1024;
    const int i = threadIdx.x * 4;
    if (*flag) {
        const float* f = (const float*)src;
        ushort4 o;
        o.x = f2bf(f[i]); o.y = f2bf(f[i + 1]);
        o.z = f2bf(f[i + 2]); o.w = f2bf(f[i + 3]);
        *(ushort4*)(d + i) = o;
    } else {
        *(ushort4*)(d + i) = *(const ushort4*)((const u16*)src + i);
    }
}

// --------------------------------------------------------------- X -> bf16
__global__ __launch_bounds__(256) void convert_x_kernel(
    const void* __restrict__ X, u16* __restrict__ Xb, const int* __restrict__ flag)
{
    const size_t i = ((size_t)blockIdx.x * 256 + threadIdx.x) * 8;
    if (*flag) {
        const float* f = (const float*)X;
        float4 a = *(const float4*)(f + i);
        float4 b = *(const float4*)(f + i + 4);
        ushort4 o0, o1;
        o0.x = f2bf(a.x); o0.y = f2bf(a.y); o0.z = f2bf(a.z); o0.w = f2bf(a.w);
        o1.x = f2bf(b.x); o1.y = f2bf(b.y); o1.z = f2bf(b.z); o1.w = f2bf(b.w);
        *(ushort4*)(Xb + i) = o0;
        *(ushort4*)(Xb + i + 4) = o1;
    } else {
        *(uint4*)(Xb + i) = *(const uint4*)((const u16*)X + i);
    }
}

// ---------------------------------------------------------------- transpose W
__global__ __launch_bounds__(256) void transpose_w_kernel(
    const void* __restrict__ Wq, const void* __restrict__ Wk,
    const void* __restrict__ Wv, u16* __restrict__ Wt,
    const int* __restrict__ flag)
{
    __shared__ u16 tile[64][72];
    const int t  = threadIdx.x;
    const int k0 = blockIdx.x * 64;
    const int n0 = blockIdx.y * 64;
    const int w  = blockIdx.z;
    const void* W = (w == 0) ? Wq : ((w == 1) ? Wk : Wv);
    const int fp32 = *flag;
#pragma unroll
    for (int it = 0; it < 2; ++it) {
        int idx = t + it * 256;
        int r = idx >> 3;
        int c = (idx & 7) * 8;
        const size_t off = (size_t)(k0 + r) * 1024 + n0 + c;
        if (fp32) {
            const float* Wf = (const float*)W + off;
            float4 a = *(const float4*)Wf;
            float4 b = *(const float4*)(Wf + 4);
            u16* tp = &tile[r][c];
            tp[0] = f2bf(a.x); tp[1] = f2bf(a.y); tp[2] = f2bf(a.z); tp[3] = f2bf(a.w);
            tp[4] = f2bf(b.x); tp[5] = f2bf(b.y); tp[6] = f2bf(b.z); tp[7] = f2bf(b.w);
        } else {
            *(uint4*)&tile[r][c] = *(const uint4*)((const u16*)W + off);
        }
    }
    __syncthreads();
#pragma unroll
    for (int it = 0; it < 2; ++it) {
        int idx = t + it * 256;
        int r = idx >> 3;
        int c = (idx & 7) * 8;
        union { u16 s[8]; uint4 v; } tmp;
#pragma unroll
        for (int j = 0; j < 8; ++j) tmp.s[j] = tile[c + j][r];
        *(uint4*)(Wt + (size_t)(w * 1024 + n0 + r) * 1024 + k0 + c) = tmp.v;
    }
}

// ------------------------------------------------------------ transpose V (4)
__global__ __launch_bounds__(256) void transpose_v4_kernel(
    const u16* __restrict__ QKV, u16* __restrict__ Vt4)
{
    __shared__ u16 tile[64][72];
    const int t  = threadIdx.x;
    const int k0 = blockIdx.x * 64;     // s
    const int n0 = blockIdx.y * 64;     // d
    const int b  = blockIdx.z;
    const u16* Vsrc = QKV + (size_t)b * 2048 * 3072 + 2048;
    u16* Vt = Vt4 + (size_t)b * 1024 * 2048;
#pragma unroll
    for (int it = 0; it < 2; ++it) {
        int idx = t + it * 256;
        int r = idx >> 3;
        int c = (idx & 7) * 8;
        *(uint4*)&tile[r][c] = *(const uint4*)(Vsrc + (size_t)(k0 + r) * 3072 + n0 + c);
    }
    __syncthreads();
#pragma unroll
    for (int it = 0; it < 2; ++it) {
        int idx = t + it * 256;
        int r = idx >> 3;
        int c = (idx & 7) * 8;
        union { u16 s[8]; uint4 v; } tmp;
#pragma unroll
        for (int j = 0; j < 8; ++j) tmp.s[j] = tile[c + j][r];
        *(uint4*)(Vt + (size_t)(n0 + r) * 2048 + k0 + c) = tmp.v;
    }
}

// ---------------------------------------------------------- GEMM 256x128x64
// C[M][N] = A[M][K] @ Bt[N][K]^T * scale (+bias), bf16 in/out, fp32 accum.
// 256 thr = 4 waves arranged 2x2; wave (wr,wc) computes 128x64 via 4x2
// 32x32x16 MFMAs (8 MFMAs per 6 frag reads per k16 = 21.3 FLOP/LDS-byte).
// BK=64 as two slabs: As[2][256*32] (16KB each) + Bs[2][128*32] (8KB each)
// = 48 KB LDS. XOR kgroup swizzle key=(row>>1)&3 (parity-independent ->
// uniform 8 words/bank). Staging lane i fetches global kgroup
// (i&3)^((i>>3)&3); LDS dest stays the contiguous DMA pattern (m104).
template<int EPI>
__global__ __launch_bounds__(256) void gemm256(
    const u16* __restrict__ A, int lda, size_t sA,
    const u16* __restrict__ Bt, int ldb, size_t sB,
    u16* __restrict__ C, int ldc, size_t sC,
    int K, float scale, const u16* __restrict__ bias3)
{
    __shared__ u16 As[2][256 * 32];
    __shared__ u16 Bs[2][128 * 32];
    const int t    = threadIdx.x;
    const int lane = t & 63;
    const int w    = t >> 6;
    const int wr   = w >> 1, wc = w & 1;
    const int m0 = blockIdx.y * 256;
    const int n0 = blockIdx.x * 128;
    A  += (size_t)blockIdx.z * sA;
    Bt += (size_t)blockIdx.z * sB;
    C  += (size_t)blockIdx.z * sC;

    // staging: wave w covers A rows [w*64, w*64+64) (4 chunks of 16) and
    // B rows [w*32, w*32+32) (2 chunks). key = (srow>>1)&3.
    const int srow = lane >> 2;
    const int skg  = (lane & 3) ^ ((srow >> 1) & 3);
    const u16* Ag[4];
#pragma unroll
    for (int c = 0; c < 4; ++c)
        Ag[c] = A + (size_t)(m0 + w * 64 + c * 16 + srow) * lda + skg * 8;
    const u16* Bg[2];
#pragma unroll
    for (int c = 0; c < 2; ++c)
        Bg[c] = Bt + (size_t)(n0 + w * 32 + c * 16 + srow) * ldb + skg * 8;

    f32x16 acc[4][2];
#pragma unroll
    for (int mi = 0; mi < 4; ++mi)
#pragma unroll
        for (int ni = 0; ni < 2; ++ni)
#pragma unroll
            for (int r = 0; r < 16; ++r)
                acc[mi][ni][r] = 0.f;

    const int ml  = lane & 31;
    const int kh  = lane >> 5;           // khalf
    const int key = (ml >> 1) & 3;       // parity-independent swizzle key

    for (int k0 = 0; k0 < K; k0 += 64) {
#pragma unroll
        for (int slab = 0; slab < 2; ++slab) {
            const int off = k0 + slab * 32;
#pragma unroll
            for (int c = 0; c < 4; ++c)
                load_lds16(Ag[c] + off, &As[slab][(w * 64 + c * 16) * 32]);
#pragma unroll
            for (int c = 0; c < 2; ++c)
                load_lds16(Bg[c] + off, &Bs[slab][(w * 32 + c * 16) * 32]);
        }
        __syncthreads();
#pragma unroll
        for (int slab = 0; slab < 2; ++slab) {
            const u16* as_ = As[slab];
            const u16* bs_ = Bs[slab];
#pragma unroll
            for (int s = 0; s < 2; ++s) {
                const int g    = s * 2 + kh;             // kgroup within slab
                const int slot = (g ^ key) * 8;
                bf16x8 af[4], bf[2];
#pragma unroll
                for (int mi = 0; mi < 4; ++mi)
                    af[mi] = *(const bf16x8*)&as_[(wr * 128 + mi * 32 + ml) * 32 + slot];
#pragma unroll
                for (int ni = 0; ni < 2; ++ni)
                    bf[ni] = *(const bf16x8*)&bs_[(wc * 64 + ni * 32 + ml) * 32 + slot];
#pragma unroll
                for (int mi = 0; mi < 4; ++mi)
#pragma unroll
                    for (int ni = 0; ni < 2; ++ni)
                        acc[mi][ni] = __builtin_amdgcn_mfma_f32_32x32x16_bf16(
                            af[mi], bf[ni], acc[mi][ni], 0, 0, 0);
            }
        }
        __syncthreads();
    }

    // C/D layout (m74/m101): col = lane&31, row = (reg&3) + 8*(reg>>2) + 4*(lane>>5)
    const int colb = n0 + wc * 64 + ml;
    const int rowb = m0 + wr * 128 + 4 * kh;
#pragma unroll
    for (int mi = 0; mi < 4; ++mi) {
#pragma unroll
        for (int ni = 0; ni < 2; ++ni) {
            const int col = colb + ni * 32;
            const float bias = (EPI == 0) ? bf2f(bias3[col]) : 0.f;
#pragma unroll
            for (int r = 0; r < 16; ++r) {
                const int row = rowb + mi * 32 + (r & 3) + 8 * (r >> 2);
                C[(size_t)row * ldc + col] = f2bf(acc[mi][ni][r] * scale + bias);
            }
        }
    }
}

// ----------------------------------------------------------- softmax (bf16)
__global__ __launch_bounds__(256) void softmax_bf16_kernel(u16* __restrict__ S)
{
    const int t = threadIdx.x;
    u16* sp = S + (size_t)blockIdx.x * 2048;
    union { uint4 v; u16 h[8]; } raw;
    raw.v = *(const uint4*)(sp + t * 8);
    float vals[8];
#pragma unroll
    for (int i = 0; i < 8; ++i) vals[i] = bf2f(raw.h[i]);
    float m = vals[0];
#pragma unroll
    for (int i = 1; i < 8; ++i) m = fmaxf(m, vals[i]);
#pragma unroll
    for (int off = 32; off > 0; off >>= 1) m = fmaxf(m, __shfl_xor(m, off));
    __shared__ float red[8];
    const int w = t >> 6, lane = t & 63;
    if (lane == 0) red[w] = m;
    __syncthreads();
    m = fmaxf(fmaxf(red[0], red[1]), fmaxf(red[2], red[3]));
    float e[8], s = 0.f;
#pragma unroll
    for (int i = 0; i < 8; ++i) { e[i] = __expf(vals[i] - m); s += e[i]; }
#pragma unroll
    for (int off = 32; off > 0; off >>= 1) s += __shfl_xor(s, off);
    if (lane == 0) red[4 + w] = s;
    __syncthreads();
    s = red[4] + red[5] + red[6] + red[7];
    const float rinv = 1.f / s;
    union { uint4 v; u16 h[8]; } out;
#pragma unroll
    for (int i = 0; i < 8; ++i) out.h[i] = f2bf(e[i] * rinv);
    *(uint4*)(sp + t * 8) = out.v;
}

// ---------------------------------------------------------------- resid + LN
__global__ __launch_bounds__(256) void resid_ln_kernel(
    const u16* __restrict__ Ctx, const u16* __restrict__ Xb,
    const u16* __restrict__ gamma, const u16* __restrict__ beta,
    void* __restrict__ Out, const int* __restrict__ flag)
{
    const size_t row = blockIdx.x;
    const int t = threadIdx.x;
    ushort4 cv = *(const ushort4*)(Ctx + row * 3072 + t * 4);
    ushort4 xv = *(const ushort4*)(Xb + row * 1024 + t * 4);
    float v[4] = {bf2f(cv.x) + bf2f(xv.x), bf2f(cv.y) + bf2f(xv.y),
                  bf2f(cv.z) + bf2f(xv.z), bf2f(cv.w) + bf2f(xv.w)};
    float s  = v[0] + v[1] + v[2] + v[3];
    float s2 = v[0] * v[0] + v[1] * v[1] + v[2] * v[2] + v[3] * v[3];
#pragma unroll
    for (int off = 32; off > 0; off >>= 1) {
        s  += __shfl_xor(s, off);
        s2 += __shfl_xor(s2, off);
    }
    __shared__ float red[8];
    const int w = t >> 6, lane = t & 63;
    if (lane == 0) { red[w] = s; red[4 + w] = s2; }
    __syncthreads();
    s  = red[0] + red[1] + red[2] + red[3];
    s2 = red[4] + red[5] + red[6] + red[7];
    const float mu  = s * (1.f / 1024.f);
    const float var = s2 * (1.f / 1024.f) - mu * mu;
    const float inv = rsqrtf(var + 1e-3f);
    ushort4 gv = *(const ushort4*)(gamma + t * 4);
    ushort4 bv = *(const ushort4*)(beta + t * 4);
    float o[4];
    o[0] = (v[0] - mu) * inv * bf2f(gv.x) + bf2f(bv.x);
    o[1] = (v[1] - mu) * inv * bf2f(gv.y) + bf2f(bv.y);
    o[2] = (v[2] - mu) * inv * bf2f(gv.z) + bf2f(bv.z);
    o[3] = (v[3] - mu) * inv * bf2f(gv.w) + bf2f(bv.w);
    if (*flag) {
        float4 fo = {o[0], o[1], o[2], o[3]};
        *(float4*)((float*)Out + row * 1024 + t * 4) = fo;
    } else {
        ushort4 bo;
        bo.x = f2bf(o[0]); bo.y = f2bf(o[1]); bo.z = f2bf(o[2]); bo.w = f2bf(o[3]);
        *(ushort4*)((u16*)Out + row * 1024 + t * 4) = bo;
    }
}

// ---------------------------------------------------------------- launch
extern "C" void kernel_launch(void* const* d_in, const int* in_sizes, int n_in,
                              void* d_out, int out_size, void* d_ws, size_t ws_size,
                              hipStream_t stream)
{
    (void)in_sizes; (void)n_in; (void)out_size; (void)ws_size;
    const void* X     = d_in[0];
    const void* Wq    = d_in[1];
    const void* bq    = d_in[2];
    const void* Wk    = d_in[3];
    const void* bk    = d_in[4];
    const void* Wv    = d_in[5];
    const void* bv    = d_in[6];
    const void* gamma = d_in[7];
    const void* beta  = d_in[8];

    char* ws = (char*)d_ws;
    int* flag  = (int*)(ws + 0);
    u16* bias5 = (u16*)(ws + 16);
    u16* Wt    = (u16*)(ws + 16384);
    u16* QKV   = (u16*)(ws + 6307840);
    u16* Xb    = (u16*)(ws + 56639488);
    u16* S4    = (u16*)(ws + 73416704);
    u16* Vt4   = (u16*)(ws + 106971136);

    detect_mode_kernel<<<1, 64, 0, stream>>>((const u16*)X, flag);
    convert_small_kernel<<<5, 256, 0, stream>>>(bq, bk, bv, gamma, beta, bias5, flag);
    convert_x_kernel<<<4096, 256, 0, stream>>>(X, Xb, flag);
    transpose_w_kernel<<<dim3(16, 16, 3), 256, 0, stream>>>(Wq, Wk, Wv, Wt, flag);

    // QKV = Xb @ Wt^T + bias   (M=8192, N=3072, K=1024)
    gemm256<0><<<dim3(3072 / 128, 8192 / 256, 1), 256, 0, stream>>>(
        Xb, 1024, 0, Wt, 1024, 0, QKV, 3072, 0, 1024, 1.f, bias5);

    // S4[b] = (Q_b @ K_b^T)/32   (M=N=2048, K=1024, z=4)
    gemm256<1><<<dim3(2048 / 128, 2048 / 256, 4), 256, 0, stream>>>(
        QKV, 3072, (size_t)2048 * 3072,
        QKV + 1024, 3072, (size_t)2048 * 3072,
        S4, 2048, (size_t)2048 * 2048, 1024, 0.03125f, nullptr);

    softmax_bf16_kernel<<<8192, 256, 0, stream>>>(S4);
    transpose_v4_kernel<<<dim3(32, 16, 4), 256, 0, stream>>>(QKV, Vt4);

    // Ctx_b = P_b @ V_b -> QKV Q slots   (M=2048, N=1024, K=2048, z=4)
    gemm256<1><<<dim3(1024 / 128, 2048 / 256, 4), 256, 0, stream>>>(
        S4, 2048, (size_t)2048 * 2048,
        Vt4, 2048, (size_t)1024 * 2048,
        QKV, 3072, (size_t)2048 * 3072, 2048, 1.f, nullptr);

    resid_ln_kernel<<<8192, 256, 0, stream>>>(
        QKV, Xb, bias5 + 3 * 1024, bias5 + 4 * 1024, d_out, flag);
}

// Round 8
// 296.642 us; speedup vs baseline: 1.2737x; 1.2737x over previous
//
#include <hip/hip_runtime.h>
#include <hip/hip_bf16.h>
#include <cstdint>
#include <cstddef>

// B=4, S=2048, D=1024. Inputs fp32 (runtime-detected per-kernel, bf16 path kept).
// GEMMs: round-6 structure (the measured local optimum): 128x128 block tile,
// BK=64 (two 16KB slabs), global_load_lds width-16 staging, parity-independent
// XOR kgroup swizzle, 4 waves x (2x2) 32x32x16 bf16 MFMAs.
// Register budget note: 84 VGPR + 64 acc = 148 -> 3 waves/SIMD. Round 7's
// 4x2 tile (276 regs) hit the >256 cliff -> 1 block/CU -> 18% MfmaUtil. Do
// not grow the accumulator past 64 regs in this structure.
//
// Pipeline (7 launches):
//   1. prep (fused): detect dtype + convert X/bias/gamma/beta -> bf16
//      + transpose W -> Wt[3072][1024]
//   2. gemm128<0>: QKV[8192][3072] = Xb @ Wt^T + bias               (bf16)
//   3. gemm128<1> z=4: S4[b][2048][2048] = (Q_b @ K_b^T)/32         (bf16)
//   4. softmax_bf16: in-place row softmax on S4 -> P                (bf16)
//   5. transpose_v4 z=4: Vt4[b][1024][2048] = V_b^T
//   6. gemm128<1> z=4: Ctx_b = P_b @ V_b -> dead Q slots of QKV     (bf16)
//   7. resid_ln: out = LN(Ctx + Xb)*gamma + beta (fp32/bf16, self-detect)
//
// d_ws layout (16B-aligned, ~118 MB):
//   bias5 @ 16           10,240   (bq|bk|bv|gamma|beta bf16)
//   Wt    @ 16,384       6,291,456
//   QKV   @ 6,307,840    50,331,648
//   Xb    @ 56,639,488   16,777,216
//   S4/P4 @ 73,416,704   33,554,432
//   Vt4   @ 106,971,136  16,777,216   (end 123,748,352)

typedef unsigned short u16;
using bf16x8 = __attribute__((ext_vector_type(8))) short;
using f32x16 = __attribute__((ext_vector_type(16))) float;

typedef __attribute__((address_space(3))) unsigned int lds_uint;
typedef const __attribute__((address_space(1))) unsigned int glob_uint;

__device__ __forceinline__ float bf2f(u16 h) {
    union { unsigned int u; float f; } c;
    c.u = ((unsigned int)h) << 16;
    return c.f;
}
__device__ __forceinline__ u16 f2bf(float f) {
    union { float f; unsigned int u; } c;
    c.f = f;
    return (u16)((c.u + 0x7fffu + ((c.u >> 16) & 1u)) >> 16);  // RNE
}
__device__ __forceinline__ void load_lds16(const void* g, void* l) {
    __builtin_amdgcn_global_load_lds((glob_uint*)g, (lds_uint*)l, 16, 0, 0);
}

// Inline dtype detection: even-index u16s of X decode as bf16 to small finite
// nonzero values iff X is bf16; fp32 mantissa halves produce huge/NaN decodes.
// Wave 0 ballots, result broadcast via LDS. Returns 1 if fp32.
__device__ __forceinline__ int detect_fp32(const u16* X, int* sflag) {
    const int t = threadIdx.x;
    if (t < 64) {
        bool bad = false, nz = false;
#pragma unroll
        for (int j = 0; j < 4; ++j) {
            float v = bf2f(X[(t * 4 + j) * 2]);
            if (!(fabsf(v) <= 1e9f)) bad = true;
            if (v != 0.f) nz = true;
        }
        unsigned long long ab = __ballot(bad);
        unsigned long long an = __ballot(nz);
        if (t == 0) *sflag = (ab != 0ull || an == 0ull) ? 1 : 0;
    }
    __syncthreads();
    return *sflag;
}

// ------------------------------------------------------------------- prep
// Fused prologue. Grid 4869 blocks x 256:
//   [0,4096):    convert X -> Xb (8 elems/thread)
//   [4096,4864): transpose W -> Wt (16x16x3 tiles of 64x64)
//   [4864,4869): convert bq,bk,bv,gamma,beta -> bias5
__global__ __launch_bounds__(256) void prep_kernel(
    const void* __restrict__ X, const void* __restrict__ Wq,
    const void* __restrict__ Wk, const void* __restrict__ Wv,
    const void* __restrict__ bq, const void* __restrict__ bk,
    const void* __restrict__ bv, const void* __restrict__ gamma,
    const void* __restrict__ beta,
    u16* __restrict__ Xb, u16* __restrict__ Wt, u16* __restrict__ bias5)
{
    __shared__ u16 tile[64][72];
    __shared__ int sflag;
    const int fp32 = detect_fp32((const u16*)X, &sflag);
    const int t   = threadIdx.x;
    const int blk = blockIdx.x;

    if (blk < 4096) {                       // ---- convert X
        const size_t i = ((size_t)blk * 256 + t) * 8;
        if (fp32) {
            const float* f = (const float*)X;
            float4 a = *(const float4*)(f + i);
            float4 b = *(const float4*)(f + i + 4);
            ushort4 o0, o1;
            o0.x = f2bf(a.x); o0.y = f2bf(a.y); o0.z = f2bf(a.z); o0.w = f2bf(a.w);
            o1.x = f2bf(b.x); o1.y = f2bf(b.y); o1.z = f2bf(b.z); o1.w = f2bf(b.w);
            *(ushort4*)(Xb + i) = o0;
            *(ushort4*)(Xb + i + 4) = o1;
        } else {
            *(uint4*)(Xb + i) = *(const uint4*)((const u16*)X + i);
        }
    } else if (blk < 4864) {                // ---- transpose W
        const int idx = blk - 4096;
        const int k0 = (idx & 15) * 64;
        const int n0 = ((idx >> 4) & 15) * 64;
        const int w  = idx >> 8;
        const void* W = (w == 0) ? Wq : ((w == 1) ? Wk : Wv);
#pragma unroll
        for (int it = 0; it < 2; ++it) {
            int i2 = t + it * 256;
            int r = i2 >> 3;
            int c = (i2 & 7) * 8;
            const size_t off = (size_t)(k0 + r) * 1024 + n0 + c;
            if (fp32) {
                const float* Wf = (const float*)W + off;
                float4 a = *(const float4*)Wf;
                float4 b = *(const float4*)(Wf + 4);
                u16* tp = &tile[r][c];
                tp[0] = f2bf(a.x); tp[1] = f2bf(a.y); tp[2] = f2bf(a.z); tp[3] = f2bf(a.w);
                tp[4] = f2bf(b.x); tp[5] = f2bf(b.y); tp[6] = f2bf(b.z); tp[7] = f2bf(b.w);
            } else {
                *(uint4*)&tile[r][c] = *(const uint4*)((const u16*)W + off);
            }
        }
        __syncthreads();
#pragma unroll
        for (int it = 0; it < 2; ++it) {
            int i2 = t + it * 256;
            int r = i2 >> 3;
            int c = (i2 & 7) * 8;
            union { u16 s[8]; uint4 v; } tmp;
#pragma unroll
            for (int j = 0; j < 8; ++j) tmp.s[j] = tile[c + j][r];
            *(uint4*)(Wt + (size_t)(w * 1024 + n0 + r) * 1024 + k0 + c) = tmp.v;
        }
    } else {                                // ---- small vectors
        const int v = blk - 4864;
        const void* srcs[5] = {bq, bk, bv, gamma, beta};
        const void* src = srcs[v];
        u16* d = bias5 + (size_t)v * 1024;
        const int i = t * 4;
        if (fp32) {
            const float* f = (const float*)src;
            ushort4 o;
            o.x = f2bf(f[i]); o.y = f2bf(f[i + 1]);
            o.z = f2bf(f[i + 2]); o.w = f2bf(f[i + 3]);
            *(ushort4*)(d + i) = o;
        } else {
            *(ushort4*)(d + i) = *(const ushort4*)((const u16*)src + i);
        }
    }
}

// ------------------------------------------------------------ transpose V (4)
__global__ __launch_bounds__(256) void transpose_v4_kernel(
    const u16* __restrict__ QKV, u16* __restrict__ Vt4)
{
    __shared__ u16 tile[64][72];
    const int t  = threadIdx.x;
    const int k0 = blockIdx.x * 64;     // s
    const int n0 = blockIdx.y * 64;     // d
    const int b  = blockIdx.z;
    const u16* Vsrc = QKV + (size_t)b * 2048 * 3072 + 2048;
    u16* Vt = Vt4 + (size_t)b * 1024 * 2048;
#pragma unroll
    for (int it = 0; it < 2; ++it) {
        int idx = t + it * 256;
        int r = idx >> 3;
        int c = (idx & 7) * 8;
        *(uint4*)&tile[r][c] = *(const uint4*)(Vsrc + (size_t)(k0 + r) * 3072 + n0 + c);
    }
    __syncthreads();
#pragma unroll
    for (int it = 0; it < 2; ++it) {
        int idx = t + it * 256;
        int r = idx >> 3;
        int c = (idx & 7) * 8;
        union { u16 s[8]; uint4 v; } tmp;
#pragma unroll
        for (int j = 0; j < 8; ++j) tmp.s[j] = tile[c + j][r];
        *(uint4*)(Vt + (size_t)(n0 + r) * 2048 + k0 + c) = tmp.v;
    }
}

// ----------------------------------------------------------- GEMM 128x128x64
// (round-6 verbatim — the measured local optimum: 727 TF on QKV)
template<int EPI>
__global__ __launch_bounds__(256) void gemm128(
    const u16* __restrict__ A, int lda, size_t sA,
    const u16* __restrict__ Bt, int ldb, size_t sB,
    u16* __restrict__ C, int ldc, size_t sC,
    int K, float scale, const u16* __restrict__ bias3)
{
    __shared__ u16 As[2][128 * 32];
    __shared__ u16 Bs[2][128 * 32];
    const int t    = threadIdx.x;
    const int lane = t & 63;
    const int w    = t >> 6;
    const int wr   = w >> 1, wc = w & 1;
    const int m0 = blockIdx.y * 128;
    const int n0 = blockIdx.x * 128;
    A  += (size_t)blockIdx.z * sA;
    Bt += (size_t)blockIdx.z * sB;
    C  += (size_t)blockIdx.z * sC;

    // swizzled staging (wave w covers rows [w*32, w*32+32)); key = (srow>>1)&3
    const int srow = lane >> 2;
    const int skg  = (lane & 3) ^ ((srow >> 1) & 3);
    const u16* Ag0 = A  + (size_t)(m0 + w * 32 +      srow) * lda + skg * 8;
    const u16* Ag1 = A  + (size_t)(m0 + w * 32 + 16 + srow) * lda + skg * 8;
    const u16* Bg0 = Bt + (size_t)(n0 + w * 32 +      srow) * ldb + skg * 8;
    const u16* Bg1 = Bt + (size_t)(n0 + w * 32 + 16 + srow) * ldb + skg * 8;
    u16* Al0 = &As[0][(w * 32) * 32];
    u16* Al1 = &As[1][(w * 32) * 32];
    u16* Bl0 = &Bs[0][(w * 32) * 32];
    u16* Bl1 = &Bs[1][(w * 32) * 32];

    f32x16 acc[2][2];
#pragma unroll
    for (int mi = 0; mi < 2; ++mi)
#pragma unroll
        for (int ni = 0; ni < 2; ++ni)
#pragma unroll
            for (int r = 0; r < 16; ++r)
                acc[mi][ni][r] = 0.f;

    const int ml  = lane & 31;
    const int kh  = lane >> 5;           // khalf
    const int key = (ml >> 1) & 3;       // parity-independent swizzle key

    for (int k0 = 0; k0 < K; k0 += 64) {
        load_lds16(Ag0 + k0,      Al0);
        load_lds16(Ag1 + k0,      Al0 + 16 * 32);
        load_lds16(Bg0 + k0,      Bl0);
        load_lds16(Bg1 + k0,      Bl0 + 16 * 32);
        load_lds16(Ag0 + k0 + 32, Al1);
        load_lds16(Ag1 + k0 + 32, Al1 + 16 * 32);
        load_lds16(Bg0 + k0 + 32, Bl1);
        load_lds16(Bg1 + k0 + 32, Bl1 + 16 * 32);
        __syncthreads();
#pragma unroll
        for (int slab = 0; slab < 2; ++slab) {
            const u16* as_ = As[slab];
            const u16* bs_ = Bs[slab];
#pragma unroll
            for (int s = 0; s < 2; ++s) {
                const int g    = s * 2 + kh;             // kgroup within slab
                const int slot = (g ^ key) * 8;
                bf16x8 a0 = *(const bf16x8*)&as_[(wr * 64 +      ml) * 32 + slot];
                bf16x8 a1 = *(const bf16x8*)&as_[(wr * 64 + 32 + ml) * 32 + slot];
                bf16x8 b0 = *(const bf16x8*)&bs_[(wc * 64 +      ml) * 32 + slot];
                bf16x8 b1 = *(const bf16x8*)&bs_[(wc * 64 + 32 + ml) * 32 + slot];
                acc[0][0] = __builtin_amdgcn_mfma_f32_32x32x16_bf16(a0, b0, acc[0][0], 0, 0, 0);
                acc[0][1] = __builtin_amdgcn_mfma_f32_32x32x16_bf16(a0, b1, acc[0][1], 0, 0, 0);
                acc[1][0] = __builtin_amdgcn_mfma_f32_32x32x16_bf16(a1, b0, acc[1][0], 0, 0, 0);
                acc[1][1] = __builtin_amdgcn_mfma_f32_32x32x16_bf16(a1, b1, acc[1][1], 0, 0, 0);
            }
        }
        __syncthreads();
    }

    // C/D layout (m74/m101): col = lane&31, row = (reg&3) + 8*(reg>>2) + 4*(lane>>5)
    const int colb = n0 + wc * 64 + ml;
    const int rowb = m0 + wr * 64 + 4 * kh;
#pragma unroll
    for (int mi = 0; mi < 2; ++mi) {
#pragma unroll
        for (int ni = 0; ni < 2; ++ni) {
            const int col = colb + ni * 32;
            const float bias = (EPI == 0) ? bf2f(bias3[col]) : 0.f;
#pragma unroll
            for (int r = 0; r < 16; ++r) {
                const int row = rowb + mi * 32 + (r & 3) + 8 * (r >> 2);
                C[(size_t)row * ldc + col] = f2bf(acc[mi][ni][r] * scale + bias);
            }
        }
    }
}

// ----------------------------------------------------------- softmax (bf16)
__global__ __launch_bounds__(256) void softmax_bf16_kernel(u16* __restrict__ S)
{
    const int t = threadIdx.x;
    u16* sp = S + (size_t)blockIdx.x * 2048;
    union { uint4 v; u16 h[8]; } raw;
    raw.v = *(const uint4*)(sp + t * 8);
    float vals[8];
#pragma unroll
    for (int i = 0; i < 8; ++i) vals[i] = bf2f(raw.h[i]);
    float m = vals[0];
#pragma unroll
    for (int i = 1; i < 8; ++i) m = fmaxf(m, vals[i]);
#pragma unroll
    for (int off = 32; off > 0; off >>= 1) m = fmaxf(m, __shfl_xor(m, off));
    __shared__ float red[8];
    const int w = t >> 6, lane = t & 63;
    if (lane == 0) red[w] = m;
    __syncthreads();
    m = fmaxf(fmaxf(red[0], red[1]), fmaxf(red[2], red[3]));
    float e[8], s = 0.f;
#pragma unroll
    for (int i = 0; i < 8; ++i) { e[i] = __expf(vals[i] - m); s += e[i]; }
#pragma unroll
    for (int off = 32; off > 0; off >>= 1) s += __shfl_xor(s, off);
    if (lane == 0) red[4 + w] = s;
    __syncthreads();
    s = red[4] + red[5] + red[6] + red[7];
    const float rinv = 1.f / s;
    union { uint4 v; u16 h[8]; } out;
#pragma unroll
    for (int i = 0; i < 8; ++i) out.h[i] = f2bf(e[i] * rinv);
    *(uint4*)(sp + t * 8) = out.v;
}

// ---------------------------------------------------------------- resid + LN
// Self-detects output dtype from raw X (same criterion as prep).
__global__ __launch_bounds__(256) void resid_ln_kernel(
    const u16* __restrict__ Ctx, const u16* __restrict__ Xb,
    const u16* __restrict__ gamma, const u16* __restrict__ beta,
    void* __restrict__ Out, const u16* __restrict__ Xraw)
{
    __shared__ int sflag;
    const int fp32 = detect_fp32(Xraw, &sflag);
    const size_t row = blockIdx.x;
    const int t = threadIdx.x;
    ushort4 cv = *(const ushort4*)(Ctx + row * 3072 + t * 4);
    ushort4 xv = *(const ushort4*)(Xb + row * 1024 + t * 4);
    float v[4] = {bf2f(cv.x) + bf2f(xv.x), bf2f(cv.y) + bf2f(xv.y),
                  bf2f(cv.z) + bf2f(xv.z), bf2f(cv.w) + bf2f(xv.w)};
    float s  = v[0] + v[1] + v[2] + v[3];
    float s2 = v[0] * v[0] + v[1] * v[1] + v[2] * v[2] + v[3] * v[3];
#pragma unroll
    for (int off = 32; off > 0; off >>= 1) {
        s  += __shfl_xor(s, off);
        s2 += __shfl_xor(s2, off);
    }
    __shared__ float red[8];
    const int w = t >> 6, lane = t & 63;
    if (lane == 0) { red[w] = s; red[4 + w] = s2; }
    __syncthreads();
    s  = red[0] + red[1] + red[2] + red[3];
    s2 = red[4] + red[5] + red[6] + red[7];
    const float mu  = s * (1.f / 1024.f);
    const float var = s2 * (1.f / 1024.f) - mu * mu;
    const float inv = rsqrtf(var + 1e-3f);
    ushort4 gv = *(const ushort4*)(gamma + t * 4);
    ushort4 bv = *(const ushort4*)(beta + t * 4);
    float o[4];
    o[0] = (v[0] - mu) * inv * bf2f(gv.x) + bf2f(bv.x);
    o[1] = (v[1] - mu) * inv * bf2f(gv.y) + bf2f(bv.y);
    o[2] = (v[2] - mu) * inv * bf2f(gv.z) + bf2f(bv.z);
    o[3] = (v[3] - mu) * inv * bf2f(gv.w) + bf2f(bv.w);
    if (fp32) {
        float4 fo = {o[0], o[1], o[2], o[3]};
        *(float4*)((float*)Out + row * 1024 + t * 4) = fo;
    } else {
        ushort4 bo;
        bo.x = f2bf(o[0]); bo.y = f2bf(o[1]); bo.z = f2bf(o[2]); bo.w = f2bf(o[3]);
        *(ushort4*)((u16*)Out + row * 1024 + t * 4) = bo;
    }
}

// ---------------------------------------------------------------- launch
extern "C" void kernel_launch(void* const* d_in, const int* in_sizes, int n_in,
                              void* d_out, int out_size, void* d_ws, size_t ws_size,
                              hipStream_t stream)
{
    (void)in_sizes; (void)n_in; (void)out_size; (void)ws_size;
    const void* X     = d_in[0];
    const void* Wq    = d_in[1];
    const void* bq    = d_in[2];
    const void* Wk    = d_in[3];
    const void* bk    = d_in[4];
    const void* Wv    = d_in[5];
    const void* bv    = d_in[6];
    const void* gamma = d_in[7];
    const void* beta  = d_in[8];

    char* ws = (char*)d_ws;
    u16* bias5 = (u16*)(ws + 16);
    u16* Wt    = (u16*)(ws + 16384);
    u16* QKV   = (u16*)(ws + 6307840);
    u16* Xb    = (u16*)(ws + 56639488);
    u16* S4    = (u16*)(ws + 73416704);
    u16* Vt4   = (u16*)(ws + 106971136);

    // 1. fused prologue
    prep_kernel<<<4869, 256, 0, stream>>>(
        X, Wq, Wk, Wv, bq, bk, bv, gamma, beta, Xb, Wt, bias5);

    // 2. QKV = Xb @ Wt^T + bias   (M=8192, N=3072, K=1024)
    gemm128<0><<<dim3(24, 64, 1), 256, 0, stream>>>(
        Xb, 1024, 0, Wt, 1024, 0, QKV, 3072, 0, 1024, 1.f, bias5);

    // 3. S4[b] = (Q_b @ K_b^T)/32   (M=N=2048, K=1024, z=4)
    gemm128<1><<<dim3(16, 16, 4), 256, 0, stream>>>(
        QKV, 3072, (size_t)2048 * 3072,
        QKV + 1024, 3072, (size_t)2048 * 3072,
        S4, 2048, (size_t)2048 * 2048, 1024, 0.03125f, nullptr);

    // 4. softmax
    softmax_bf16_kernel<<<8192, 256, 0, stream>>>(S4);

    // 5. V^T
    transpose_v4_kernel<<<dim3(32, 16, 4), 256, 0, stream>>>(QKV, Vt4);

    // 6. Ctx_b = P_b @ V_b -> QKV Q slots   (M=2048, N=1024, K=2048, z=4)
    gemm128<1><<<dim3(8, 16, 4), 256, 0, stream>>>(
        S4, 2048, (size_t)2048 * 2048,
        Vt4, 2048, (size_t)1024 * 2048,
        QKV, 3072, (size_t)2048 * 3072, 2048, 1.f, nullptr);

    // 7. LN
    resid_ln_kernel<<<8192, 256, 0, stream>>>(
        QKV, Xb, bias5 + 3 * 1024, bias5 + 4 * 1024, d_out, (const u16*)X);
}